// Round 2
// baseline (242.795 us; speedup 1.0000x reference)
//
#include <hip/hip_runtime.h>
#include <hip/hip_bf16.h>

#define BS    8
#define NQ    16384
#define CDIM  128
#define NH    8
#define NP    4
#define HD    16
#define RES   128
#define NPROJ 224            // 128 value + 64 off + 32 attn logits
#define M_TOTAL (BS*NQ)      // 131072 rows

typedef __bf16 bf16_t;
typedef __bf16 bf16x8 __attribute__((ext_vector_type(8)));
typedef __bf16 bf16x4 __attribute__((ext_vector_type(4)));
typedef float  f32x4  __attribute__((ext_vector_type(4)));

__device__ __forceinline__ bf16x8 cvt_bf16x8(const float* p) {
    float4 a = *(const float4*)p;
    float4 b = *(const float4*)(p + 4);
    bf16x8 r;
    r[0] = (bf16_t)a.x; r[1] = (bf16_t)a.y; r[2] = (bf16_t)a.z; r[3] = (bf16_t)a.w;
    r[4] = (bf16_t)b.x; r[5] = (bf16_t)b.y; r[6] = (bf16_t)b.z; r[7] = (bf16_t)b.w;
    return r;
}

// ---------------------------------------------------------------------------
// Kernel 1: fused projections  P = query @ [Wv | Woff | Wattn] + bias
//   cols   0..127 -> value (bf16, ws)
//   cols 128..191 -> offsets (fp32, ws)
//   cols 192..223 -> attn logits (fp32, ws)
// fp32 inputs converted to bf16 for MFMA 16x16x32 (fp32 accumulate).
// ---------------------------------------------------------------------------
__global__ __launch_bounds__(256, 2)
void proj_kernel(const float* __restrict__ query,
                 const float* __restrict__ Wv,    const float* __restrict__ bv,
                 const float* __restrict__ Woff,  const float* __restrict__ boff,
                 const float* __restrict__ Wattn, const float* __restrict__ battn,
                 bf16_t* __restrict__ value, float* __restrict__ off,
                 float* __restrict__ attnl)
{
    __shared__ bf16_t Bt[NPROJ][136];   // transposed weights (bf16), padded
    __shared__ float  bias[NPROJ];
    const int t = threadIdx.x;

    for (int i = t; i < 128*128; i += 256) { int k = i >> 7, n = i & 127; Bt[n][k]     = (bf16_t)Wv[i]; }
    for (int i = t; i < 128*64;  i += 256) { int k = i >> 6, n = i & 63;  Bt[128+n][k] = (bf16_t)Woff[i]; }
    for (int i = t; i < 128*32;  i += 256) { int k = i >> 5, n = i & 31;  Bt[192+n][k] = (bf16_t)Wattn[i]; }
    if (t < 128)      bias[t] = bv[t];
    else if (t < 192) bias[t] = boff[t-128];
    else if (t < 224) bias[t] = battn[t-192];
    __syncthreads();

    const int lane = t & 63;
    const int wave = t >> 6;
    const int ln   = lane & 15;        // A row / B col / D col within tile
    const int lk   = (lane >> 4) * 8;  // k offset within 32-chunk
    const int drow = (lane >> 4) * 4;  // D row base

    const int row_base = blockIdx.x * 256 + wave * 64;

    // A fragments: 4 row-tiles x 4 k-chunks, fp32 loads converted to bf16
    bf16x8 a[4][4];
    #pragma unroll
    for (int ti = 0; ti < 4; ++ti) {
        const float* ap = query + (size_t)(row_base + ti*16 + ln) * CDIM + lk;
        #pragma unroll
        for (int kc = 0; kc < 4; ++kc)
            a[ti][kc] = cvt_bf16x8(ap + kc*32);
    }

    #pragma unroll 1
    for (int cb = 0; cb < 14; ++cb) {
        const int n0 = cb * 16;
        bf16x8 bfrag[4];
        const bf16_t* bp = &Bt[n0 + ln][lk];
        #pragma unroll
        for (int kc = 0; kc < 4; ++kc)
            bfrag[kc] = *(const bf16x8*)(bp + kc*32);
        const int   col = n0 + ln;
        const float bi  = bias[col];

        #pragma unroll
        for (int ti = 0; ti < 4; ++ti) {
            f32x4 acc = {0.f, 0.f, 0.f, 0.f};
            #pragma unroll
            for (int kc = 0; kc < 4; ++kc)
                acc = __builtin_amdgcn_mfma_f32_16x16x32_bf16(a[ti][kc], bfrag[kc], acc, 0, 0, 0);
            const int r0 = row_base + ti*16 + drow;
            if (col < 128) {
                #pragma unroll
                for (int r = 0; r < 4; ++r)
                    value[(size_t)(r0 + r)*CDIM + col] = (bf16_t)(acc[r] + bi);
            } else if (col < 192) {
                #pragma unroll
                for (int r = 0; r < 4; ++r)
                    off[(size_t)(r0 + r)*64 + (col - 128)] = acc[r] + bi;
            } else {
                #pragma unroll
                for (int r = 0; r < 4; ++r)
                    attnl[(size_t)(r0 + r)*32 + (col - 192)] = acc[r] + bi;
            }
        }
    }
}

// ---------------------------------------------------------------------------
// Kernel 2: softmax over P + bilinear deformable sampling.
// 4 lanes per (b,q,h); lane j handles hd elements [4j..4j+3].
// Writes sampled (bs,Nq,C) fp32 directly into d_out.
// ---------------------------------------------------------------------------
__global__ __launch_bounds__(256)
void sample_kernel(const bf16_t* __restrict__ value, const float* __restrict__ off,
                   const float* __restrict__ attnl, float* __restrict__ sampled)
{
    const int tid  = blockIdx.x * 256 + threadIdx.x;   // BS*NQ*NH*4 threads
    const int unit = tid >> 2;                         // (b*NQ+q)*NH + h
    const int j4   = (tid & 3) * 4;
    const int bq   = unit >> 3;                        // b*NQ + q
    const int h    = unit & 7;
    const int q    = bq & (NQ - 1);
    const int b    = bq >> 14;

    const float refx = (float)(q & 127) * (1.0f/127.0f);
    const float refy = (float)(q >> 7)  * (1.0f/127.0f);

    // softmax over the 4 points
    const float* lp = attnl + (size_t)bq*32 + h*4;
    float l0 = lp[0], l1 = lp[1], l2 = lp[2], l3 = lp[3];
    float mx = fmaxf(fmaxf(l0, l1), fmaxf(l2, l3));
    float e0 = __expf(l0-mx), e1 = __expf(l1-mx), e2 = __expf(l2-mx), e3 = __expf(l3-mx);
    float rs = 1.0f / (e0 + e1 + e2 + e3);
    float aw[4] = {e0*rs, e1*rs, e2*rs, e3*rs};

    const float*  op    = off + (size_t)bq*64 + h*8;
    const bf16_t* vbase = value + (size_t)b*NQ*CDIM + h*HD + j4;

    float a0 = 0.f, a1 = 0.f, a2 = 0.f, a3 = 0.f;
    #pragma unroll
    for (int p = 0; p < 4; ++p) {
        float x = refx * 128.0f + op[p*2 + 0] - 0.5f;
        float y = refy * 128.0f + op[p*2 + 1] - 0.5f;
        float xf = floorf(x), yf = floorf(y);
        int   x0 = (int)xf,  y0 = (int)yf;
        float wx1 = x - xf, wy1 = y - yf;
        float wx0 = 1.0f - wx1, wy0 = 1.0f - wy1;

        #pragma unroll
        for (int ty = 0; ty < 2; ++ty) {
            #pragma unroll
            for (int tx = 0; tx < 2; ++tx) {
                int xi = x0 + tx, yi = y0 + ty;
                float w = aw[p] * (tx ? wx1 : wx0) * (ty ? wy1 : wy0);
                bool valid = ((unsigned)xi < 128u) && ((unsigned)yi < 128u);
                float wv = valid ? w : 0.0f;
                int xc = min(max(xi, 0), 127), yc = min(max(yi, 0), 127);
                int idx = yc * 128 + xc;
                bf16x4 v = *(const bf16x4*)(vbase + (size_t)idx * CDIM);
                a0 += wv * (float)v[0];
                a1 += wv * (float)v[1];
                a2 += wv * (float)v[2];
                a3 += wv * (float)v[3];
            }
        }
    }
    float4 o; o.x = a0; o.y = a1; o.z = a2; o.w = a3;
    *(float4*)(sampled + (size_t)bq*CDIM + h*HD + j4) = o;
}

// ---------------------------------------------------------------------------
// Kernel 3: out = sampled @ Wout + bout + 2*query   (in-place on d_out, fp32;
// per-row byte ranges identical for load/store; each wave loads its rows into
// registers before storing them -> race-free)
// ---------------------------------------------------------------------------
__global__ __launch_bounds__(256, 2)
void out_kernel(const float* sampled, const float* __restrict__ Wout,
                const float* __restrict__ bout, const float* __restrict__ query,
                float* out)
{
    __shared__ bf16_t Bt[128][136];
    __shared__ float  bias[128];
    const int t = threadIdx.x;

    for (int i = t; i < 128*128; i += 256) { int k = i >> 7, n = i & 127; Bt[n][k] = (bf16_t)Wout[i]; }
    if (t < 128) bias[t] = bout[t];
    __syncthreads();

    const int lane = t & 63;
    const int wave = t >> 6;
    const int ln   = lane & 15;
    const int lk   = (lane >> 4) * 8;
    const int drow = (lane >> 4) * 4;

    const int row_base = blockIdx.x * 256 + wave * 64;

    bf16x8 a[4][4];
    #pragma unroll
    for (int ti = 0; ti < 4; ++ti) {
        const float* ap = sampled + (size_t)(row_base + ti*16 + ln) * CDIM + lk;
        #pragma unroll
        for (int kc = 0; kc < 4; ++kc)
            a[ti][kc] = cvt_bf16x8(ap + kc*32);
    }

    #pragma unroll 1
    for (int cb = 0; cb < 8; ++cb) {
        const int n0 = cb * 16;
        bf16x8 bfrag[4];
        const bf16_t* bp = &Bt[n0 + ln][lk];
        #pragma unroll
        for (int kc = 0; kc < 4; ++kc)
            bfrag[kc] = *(const bf16x8*)(bp + kc*32);
        const int   col = n0 + ln;
        const float bi  = bias[col];

        #pragma unroll
        for (int ti = 0; ti < 4; ++ti) {
            f32x4 acc = {0.f, 0.f, 0.f, 0.f};
            #pragma unroll
            for (int kc = 0; kc < 4; ++kc)
                acc = __builtin_amdgcn_mfma_f32_16x16x32_bf16(a[ti][kc], bfrag[kc], acc, 0, 0, 0);
            const int r0 = row_base + ti*16 + drow;
            #pragma unroll
            for (int r = 0; r < 4; ++r) {
                const size_t qi = (size_t)(r0 + r)*CDIM + col;
                out[qi] = acc[r] + bi + 2.0f * query[qi];
            }
        }
    }
}

// ---------------------------------------------------------------------------
extern "C" void kernel_launch(void* const* d_in, const int* in_sizes, int n_in,
                              void* d_out, int out_size, void* d_ws, size_t ws_size,
                              hipStream_t stream)
{
    const float* query = (const float*)d_in[0];
    const float* Wv    = (const float*)d_in[1];
    const float* bv    = (const float*)d_in[2];
    const float* Woff  = (const float*)d_in[3];
    const float* boff  = (const float*)d_in[4];
    const float* Wattn = (const float*)d_in[5];
    const float* battn = (const float*)d_in[6];
    const float* Wout  = (const float*)d_in[7];
    const float* bout  = (const float*)d_in[8];
    float* out = (float*)d_out;

    // ws layout: value bf16 (33.5MB) | off fp32 (33.5MB) | attnl fp32 (16.8MB)
    bf16_t* value = (bf16_t*)d_ws;
    float*  off   = (float*)((char*)d_ws + (size_t)M_TOTAL*CDIM*2);
    float*  attnl = (float*)((char*)d_ws + (size_t)M_TOTAL*CDIM*2 + (size_t)M_TOTAL*64*4);

    proj_kernel<<<M_TOTAL/256, 256, 0, stream>>>(query, Wv, bv, Woff, boff,
                                                 Wattn, battn, value, off, attnl);
    // sampled (fp32) goes straight into d_out, consumed in-place by out_kernel
    sample_kernel<<<(BS*NQ*NH*4)/256, 256, 0, stream>>>(value, off, attnl, out);
    out_kernel<<<M_TOTAL/256, 256, 0, stream>>>(out, Wout, bout, query, out);
}